// Round 23
// baseline (328.266 us; speedup 1.0000x reference)
//
#include <hip/hip_runtime.h>
#include <math.h>

#define BB     1024
#define CC     256
#define HWN    361
#define SEH    64
#define P3C    768
#define SLICE  (CC * HWN)      // 92416 floats per batch row
#define NW     16

typedef _Float16 f16x2 __attribute__((ext_vector_type(2)));

__device__ __forceinline__ unsigned pack2(float a, float b) {
    f16x2 h; h[0] = (_Float16)a; h[1] = (_Float16)b;
    return __builtin_bit_cast(unsigned, h);
}

// ===== ABLATION: R12's pool + MLP (no apply), gamma/beta -> ws =====
// dur(this) - dur(pool_only=79us) isolates the MLP phase cost.
__global__ __launch_bounds__(1024, 4) void k_pool_mlp(
        const float* __restrict__ x,
        const float* __restrict__ mask,
        const float* __restrict__ msum,
        const float* __restrict__ msqrt,
        const float* __restrict__ w1,
        const float* __restrict__ b1,
        const float* __restrict__ w2,
        const float* __restrict__ b2,
        float* __restrict__ ws) {
    __shared__ float m_s[HWN];
    __shared__ float p_s[P3C];
    __shared__ float part_s[NW * SEH];
    __shared__ float hid_s[SEH];

    const int tid  = threadIdx.x;
    const int lane = tid & 63;
    const int wv   = tid >> 6;
    const int b    = blockIdx.x;

    const float* xb = x + (size_t)b * SLICE;

    if (tid < HWN) m_s[tid] = mask[(size_t)b * HWN + tid];
    __syncthreads();

    const float inv_div = 1.0f / msum[b];
    const float bscale  = (msqrt[b] - 14.0f) * 0.1f;

    const int  i5   = lane + 320;
    const int  a5   = (i5 < HWN) ? i5 : (HWN - 1);
    const bool tail = (lane < 41);

    #pragma unroll
    for (int k = 0; k < 16; k += 2) {
        const int c0 = wv * 16 + k;
        const float* r0 = xb + c0 * HWN;
        const float* r1 = r0 + HWN;
        float v[6], w[6];
        #pragma unroll
        for (int ii = 0; ii < 5; ++ii) {
            v[ii] = r0[lane + ii * 64];
            w[ii] = r1[lane + ii * 64];
        }
        v[5] = r0[a5];
        w[5] = r1[a5];

        float s0 = 0.0f, s1 = 0.0f, x0 = -INFINITY, x1 = -INFINITY;
        #pragma unroll
        for (int ii = 0; ii < 5; ++ii) {
            const float pen = (1.0f - m_s[lane + ii * 64]) * -5000.0f;
            s0 += v[ii];  x0 = fmaxf(x0, v[ii] + pen);
            s1 += w[ii];  x1 = fmaxf(x1, w[ii] + pen);
        }
        if (tail) {
            const float pen = (1.0f - m_s[i5]) * -5000.0f;
            s0 += v[5];   x0 = fmaxf(x0, v[5] + pen);
            s1 += w[5];   x1 = fmaxf(x1, w[5] + pen);
        }
        #pragma unroll
        for (int off = 32; off; off >>= 1) {
            s0 += __shfl_xor(s0, off);  x0 = fmaxf(x0, __shfl_xor(x0, off));
            s1 += __shfl_xor(s1, off);  x1 = fmaxf(x1, __shfl_xor(x1, off));
        }
        if (lane == 0) {
            const float mean0 = s0 * inv_div, mean1 = s1 * inv_div;
            p_s[c0]           = mean0;
            p_s[256 + c0]     = mean0 * bscale;
            p_s[512 + c0]     = x0;
            p_s[c0 + 1]       = mean1;
            p_s[256 + c0 + 1] = mean1 * bscale;
            p_s[512 + c0 + 1] = x1;
        }
    }
    __syncthreads();

    {
        const int q = tid >> 6, s = tid & 63;
        const float* w1r = w1  + s * P3C + q * 48;
        const float* pp  = p_s + q * 48;
        float acc = 0.0f;
        #pragma unroll 8
        for (int j = 0; j < 48; ++j) acc = fmaf(pp[j], w1r[j], acc);
        part_s[q * SEH + s] = acc;
    }
    __syncthreads();
    if (tid < SEH) {
        float h = b1[tid];
        #pragma unroll
        for (int q = 0; q < NW; ++q) h += part_s[q * SEH + tid];
        hid_s[tid] = fmaxf(h, 0.0f);
    }
    __syncthreads();
    if (tid < 512) {
        float a = b2[tid];
        const float* w2r = w2 + (size_t)tid * SEH;
        #pragma unroll 8
        for (int ss = 0; ss < SEH; ++ss) a = fmaf(hid_s[ss], w2r[ss], a);
        if (tid < 256) ws[(size_t)b * 512 + tid] = 1.0f / (1.0f + __expf(-a));
        else           ws[(size_t)b * 512 + tid] = a;
    }
}

// ===== CHAMPION (R12 verbatim) =====
__global__ __launch_bounds__(1024, 4) void k_se_fused(
        const float* __restrict__ x,
        const float* __restrict__ mask,
        const float* __restrict__ msum,
        const float* __restrict__ msqrt,
        const float* __restrict__ w1,
        const float* __restrict__ b1,
        const float* __restrict__ w2,
        const float* __restrict__ b2,
        float* __restrict__ out) {
    __shared__ float m_s[HWN];
    __shared__ float p_s[P3C];
    __shared__ float part_s[NW * SEH];
    __shared__ float hid_s[SEH];
    __shared__ float g_s[CC];
    __shared__ float be_s[CC];

    const int tid  = threadIdx.x;
    const int lane = tid & 63;
    const int wv   = tid >> 6;
    const int b    = blockIdx.x;

    const float* xb = x + (size_t)b * SLICE;

    if (tid < HWN) m_s[tid] = mask[(size_t)b * HWN + tid];
    __syncthreads();

    const float inv_div = 1.0f / msum[b];
    const float bscale  = (msqrt[b] - 14.0f) * 0.1f;

    const int  i5   = lane + 320;
    const int  a5   = (i5 < HWN) ? i5 : (HWN - 1);
    const bool tail = (lane < 41);

    unsigned pk[16][3];

    #pragma unroll
    for (int k = 0; k < 16; k += 2) {
        const int c0 = wv * 16 + k;
        const float* r0 = xb + c0 * HWN;
        const float* r1 = r0 + HWN;
        float v[6], w[6];
        #pragma unroll
        for (int ii = 0; ii < 5; ++ii) {
            v[ii] = r0[lane + ii * 64];
            w[ii] = r1[lane + ii * 64];
        }
        v[5] = r0[a5];
        w[5] = r1[a5];

        pk[k][0]     = pack2(v[0], v[1]);
        pk[k][1]     = pack2(v[2], v[3]);
        pk[k][2]     = pack2(v[4], v[5]);
        pk[k + 1][0] = pack2(w[0], w[1]);
        pk[k + 1][1] = pack2(w[2], w[3]);
        pk[k + 1][2] = pack2(w[4], w[5]);
        asm volatile("" : "+v"(pk[k][0]), "+v"(pk[k][1]), "+v"(pk[k][2]),
                          "+v"(pk[k+1][0]), "+v"(pk[k+1][1]), "+v"(pk[k+1][2]));

        float s0 = 0.0f, s1 = 0.0f, x0 = -INFINITY, x1 = -INFINITY;
        #pragma unroll
        for (int ii = 0; ii < 5; ++ii) {
            const float pen = (1.0f - m_s[lane + ii * 64]) * -5000.0f;
            s0 += v[ii];  x0 = fmaxf(x0, v[ii] + pen);
            s1 += w[ii];  x1 = fmaxf(x1, w[ii] + pen);
        }
        if (tail) {
            const float pen = (1.0f - m_s[i5]) * -5000.0f;
            s0 += v[5];   x0 = fmaxf(x0, v[5] + pen);
            s1 += w[5];   x1 = fmaxf(x1, w[5] + pen);
        }
        #pragma unroll
        for (int off = 32; off; off >>= 1) {
            s0 += __shfl_xor(s0, off);  x0 = fmaxf(x0, __shfl_xor(x0, off));
            s1 += __shfl_xor(s1, off);  x1 = fmaxf(x1, __shfl_xor(x1, off));
        }
        if (lane == 0) {
            const float mean0 = s0 * inv_div, mean1 = s1 * inv_div;
            p_s[c0]           = mean0;
            p_s[256 + c0]     = mean0 * bscale;
            p_s[512 + c0]     = x0;
            p_s[c0 + 1]       = mean1;
            p_s[256 + c0 + 1] = mean1 * bscale;
            p_s[512 + c0 + 1] = x1;
        }
    }
    __syncthreads();

    {
        const int q = tid >> 6, s = tid & 63;
        const float* w1r = w1  + s * P3C + q * 48;
        const float* pp  = p_s + q * 48;
        float acc = 0.0f;
        #pragma unroll 8
        for (int j = 0; j < 48; ++j) acc = fmaf(pp[j], w1r[j], acc);
        part_s[q * SEH + s] = acc;
    }
    __syncthreads();
    if (tid < SEH) {
        float h = b1[tid];
        #pragma unroll
        for (int q = 0; q < NW; ++q) h += part_s[q * SEH + tid];
        hid_s[tid] = fmaxf(h, 0.0f);
    }
    __syncthreads();

    if (tid < 512) {
        float a = b2[tid];
        const float* w2r = w2 + (size_t)tid * SEH;
        #pragma unroll 8
        for (int ss = 0; ss < SEH; ++ss) a = fmaf(hid_s[ss], w2r[ss], a);
        if (tid < 256) g_s[tid]        = 1.0f / (1.0f + __expf(-a));
        else           be_s[tid - 256] = a;
    }
    __syncthreads();

    float* ob = out + (size_t)b * SLICE;
    #pragma unroll
    for (int k = 0; k < 16; ++k) {
        const int c  = wv * 16 + k;
        const float g  = g_s[c];
        const float be = be_s[c];
        float* orow = ob + c * HWN;
        const f16x2 h0 = __builtin_bit_cast(f16x2, pk[k][0]);
        const f16x2 h1 = __builtin_bit_cast(f16x2, pk[k][1]);
        const f16x2 h2 = __builtin_bit_cast(f16x2, pk[k][2]);
        orow[lane]       = fmaf(g, (float)h0[0], be) * m_s[lane];
        orow[lane + 64]  = fmaf(g, (float)h0[1], be) * m_s[lane + 64];
        orow[lane + 128] = fmaf(g, (float)h1[0], be) * m_s[lane + 128];
        orow[lane + 192] = fmaf(g, (float)h1[1], be) * m_s[lane + 192];
        orow[lane + 256] = fmaf(g, (float)h2[0], be) * m_s[lane + 256];
        if (tail)
            orow[i5]     = fmaf(g, (float)h2[1], be) * m_s[i5];
    }
}

extern "C" void kernel_launch(void* const* d_in, const int* in_sizes, int n_in,
                              void* d_out, int out_size, void* d_ws, size_t ws_size,
                              hipStream_t stream) {
    const float* x     = (const float*)d_in[0];
    const float* mask  = (const float*)d_in[1];
    const float* msum  = (const float*)d_in[2];
    const float* msqrt = (const float*)d_in[3];
    const float* w1    = (const float*)d_in[4];
    const float* b1    = (const float*)d_in[5];
    const float* w2    = (const float*)d_in[6];
    const float* b2    = (const float*)d_in[7];
    float* out = (float*)d_out;
    float* ws  = (float*)d_ws;

    // Ablation: pool + MLP only (gamma/beta -> ws; result unused downstream).
    k_pool_mlp<<<BB, 1024, 0, stream>>>(x, mask, msum, msqrt,
                                        w1, b1, w2, b2, ws);
    // Champion (R12): full fused computation, writes d_out.
    k_se_fused<<<BB, 1024, 0, stream>>>(x, mask, msum, msqrt,
                                        w1, b1, w2, b2, out);
}

// Round 24
// 239.869 us; speedup vs baseline: 1.3685x; 1.3685x over previous
//
#include <hip/hip_runtime.h>
#include <math.h>

#define BB     1024
#define CC     256
#define HWN    361
#define SEH    64
#define P3C    768
#define SLICE  (CC * HWN)      // 92416 floats per batch row
#define SLICE4 (SLICE / 4)     // 23104 f32x4 per batch row
#define NW     16

typedef float    f32x4 __attribute__((ext_vector_type(4)));
typedef _Float16 f16x2 __attribute__((ext_vector_type(2)));

__device__ __forceinline__ unsigned pack2(float a, float b) {
    f16x2 h; h[0] = (_Float16)a; h[1] = (_Float16)b;
    return __builtin_bit_cast(unsigned, h);
}

// ===== Kernel A: pool + f16 copy. NT x-loads (no L3 alloc); ws copy owns L3.
__global__ __launch_bounds__(1024, 4) void k_pool_copy(
        const float* __restrict__ x,
        const float* __restrict__ mask,
        const float* __restrict__ msum,
        const float* __restrict__ msqrt,
        unsigned* __restrict__ wsd,        // f16-pair dwords, 192/row
        float* __restrict__ pooled) {
    __shared__ float m_s[HWN];
    __shared__ float p_s[P3C];

    const int tid  = threadIdx.x;
    const int lane = tid & 63;
    const int wv   = tid >> 6;
    const int b    = blockIdx.x;

    const float* xb = x + (size_t)b * SLICE;

    if (tid < HWN) m_s[tid] = mask[(size_t)b * HWN + tid];
    __syncthreads();

    const float inv_div = 1.0f / msum[b];
    const float bscale  = (msqrt[b] - 14.0f) * 0.1f;   // (sqrt(div)-B_AVG)/10

    const int  i5   = lane + 320;
    const int  a5   = (i5 < HWN) ? i5 : (HWN - 1);
    const bool tail = (lane < 41);

    #pragma unroll
    for (int k = 0; k < 16; k += 2) {
        const int c0 = wv * 16 + k;
        const float* r0 = xb + c0 * HWN;
        const float* r1 = r0 + HWN;
        float v[6], w[6];
        #pragma unroll
        for (int ii = 0; ii < 5; ++ii) {
            v[ii] = __builtin_nontemporal_load(r0 + lane + ii * 64);
            w[ii] = __builtin_nontemporal_load(r1 + lane + ii * 64);
        }
        v[5] = __builtin_nontemporal_load(r0 + a5);
        w[5] = __builtin_nontemporal_load(r1 + a5);

        // f16 copy: 3 dwords per row per lane, coalesced (regular stores -> L3)
        {
            const size_t g0 = ((size_t)b * CC + c0) * 192;
            wsd[g0 + lane]        = pack2(v[0], v[1]);
            wsd[g0 + 64 + lane]   = pack2(v[2], v[3]);
            wsd[g0 + 128 + lane]  = pack2(v[4], v[5]);
            wsd[g0 + 192 + lane]       = pack2(w[0], w[1]);
            wsd[g0 + 192 + 64 + lane]  = pack2(w[2], w[3]);
            wsd[g0 + 192 + 128 + lane] = pack2(w[4], w[5]);
        }

        float s0 = 0.0f, s1 = 0.0f, x0 = -INFINITY, x1 = -INFINITY;
        #pragma unroll
        for (int ii = 0; ii < 5; ++ii) {
            const float pen = (1.0f - m_s[lane + ii * 64]) * -5000.0f;
            s0 += v[ii];  x0 = fmaxf(x0, v[ii] + pen);
            s1 += w[ii];  x1 = fmaxf(x1, w[ii] + pen);
        }
        if (tail) {
            const float pen = (1.0f - m_s[i5]) * -5000.0f;
            s0 += v[5];   x0 = fmaxf(x0, v[5] + pen);
            s1 += w[5];   x1 = fmaxf(x1, w[5] + pen);
        }
        #pragma unroll
        for (int off = 32; off; off >>= 1) {
            s0 += __shfl_xor(s0, off);  x0 = fmaxf(x0, __shfl_xor(x0, off));
            s1 += __shfl_xor(s1, off);  x1 = fmaxf(x1, __shfl_xor(x1, off));
        }
        if (lane == 0) {
            const float mean0 = s0 * inv_div, mean1 = s1 * inv_div;
            p_s[c0]           = mean0;
            p_s[256 + c0]     = mean0 * bscale;
            p_s[512 + c0]     = x0;
            p_s[c0 + 1]       = mean1;
            p_s[256 + c0 + 1] = mean1 * bscale;
            p_s[512 + c0 + 1] = x1;
        }
    }
    __syncthreads();
    if (tid < P3C) pooled[(size_t)b * P3C + tid] = p_s[tid];
}

// ===== Kernel B: tiny MLP, 4 b per block (R1-proven) =====
__global__ __launch_bounds__(256) void k_mlp(
        const float* __restrict__ pooled,
        const float* __restrict__ w1,
        const float* __restrict__ b1,
        const float* __restrict__ w2,
        const float* __restrict__ b2,
        float* __restrict__ gb) {
    __shared__ float plds[4 * P3C];
    __shared__ float hlds[4 * SEH];
    const int t  = threadIdx.x;
    const int b0 = blockIdx.x * 4;

    #pragma unroll
    for (int i = 0; i < 12; ++i)
        plds[t + i * 256] = pooled[(size_t)b0 * P3C + t + i * 256];
    __syncthreads();

    {   // layer 1
        const int bb = t >> 6, s = t & 63;
        float acc = b1[s];
        const float* w1r = w1   + s  * P3C;
        const float* pr  = plds + bb * P3C;
        #pragma unroll 8
        for (int j = 0; j < P3C; ++j) acc = fmaf(pr[j], w1r[j], acc);
        hlds[bb * SEH + s] = fmaxf(acc, 0.0f);
    }
    __syncthreads();

    #pragma unroll
    for (int k = 0; k < 8; ++k) {     // layer 2: 2048 dots, 8/thread
        int q  = k * 256 + t;
        int rb = q >> 9;
        int o  = q & 511;
        float a = b2[o];
        const float* w2r = w2   + o  * SEH;
        const float* hr  = hlds + rb * SEH;
        #pragma unroll 8
        for (int ss = 0; ss < SEH; ++ss) a = fmaf(hr[ss], w2r[ss], a);
        int b = b0 + rb;
        if (o < 256) gb[(size_t)b * 512 + o] = 1.0f / (1.0f + __expf(-a));
        else         gb[(size_t)b * 512 + o] = a;
    }
}

// ===== Kernel C: apply from L3-resident f16 copy; NT f32x4 stores =====
__global__ __launch_bounds__(1024) void k_apply_f16(
        const unsigned* __restrict__ wsd,
        const float* __restrict__ mask,
        const float* __restrict__ gb,
        float* __restrict__ out) {
    __shared__ f32x4 stage4[NW][361];   // 92.4 KB wave-private staging
    __shared__ float m_s[HWN];
    __shared__ float g_s[CC];
    __shared__ float be_s[CC];

    const int tid  = threadIdx.x;
    const int lane = tid & 63;
    const int wv   = tid >> 6;
    const int b    = blockIdx.x;

    if (tid < HWN) m_s[tid] = mask[(size_t)b * HWN + tid];
    if (tid < 256)      g_s[tid]        = gb[(size_t)b * 512 + tid];
    else if (tid < 512) be_s[tid - 256] = gb[(size_t)b * 512 + tid];
    __syncthreads();

    const bool tail = (lane < 41);
    const int  i5   = lane + 320;
    f32x4* oq = (f32x4*)(out + (size_t)b * SLICE);
    float* st = (float*)&stage4[wv][0];

    #pragma unroll
    for (int gg = 0; gg < 4; ++gg) {
        const int c0 = wv * 16 + gg * 4;
        #pragma unroll
        for (int r = 0; r < 4; ++r) {
            const int row = c0 + r;
            const unsigned* wr = wsd + ((size_t)b * CC + row) * 192;
            const unsigned d0 = wr[lane];
            const unsigned d1 = wr[64 + lane];
            const unsigned d2 = wr[128 + lane];
            const float gv  = g_s[row];
            const float bev = be_s[row];
            const f16x2 h0 = __builtin_bit_cast(f16x2, d0);
            const f16x2 h1 = __builtin_bit_cast(f16x2, d1);
            const f16x2 h2 = __builtin_bit_cast(f16x2, d2);
            st[r * 361 + lane]       = fmaf(gv, (float)h0[0], bev) * m_s[lane];
            st[r * 361 + lane + 64]  = fmaf(gv, (float)h0[1], bev) * m_s[lane + 64];
            st[r * 361 + lane + 128] = fmaf(gv, (float)h1[0], bev) * m_s[lane + 128];
            st[r * 361 + lane + 192] = fmaf(gv, (float)h1[1], bev) * m_s[lane + 192];
            st[r * 361 + lane + 256] = fmaf(gv, (float)h2[0], bev) * m_s[lane + 256];
            if (tail)
                st[r * 361 + i5]     = fmaf(gv, (float)h2[1], bev) * m_s[i5];
        }
        // wave-private: ds ordering within the wave suffices (no barrier)
        const int qb = (wv * 4 + gg) * 361;     // 4-row group = 361 aligned quads
        #pragma unroll
        for (int jj = 0; jj < 5; ++jj)
            __builtin_nontemporal_store(stage4[wv][lane + 64 * jj],
                                        &oq[qb + lane + 64 * jj]);
        if (tail)
            __builtin_nontemporal_store(stage4[wv][lane + 320], &oq[qb + lane + 320]);
    }
}

// ===== Fallback champion (R12 verbatim) =====
__global__ __launch_bounds__(1024, 4) void k_se_fused(
        const float* __restrict__ x,
        const float* __restrict__ mask,
        const float* __restrict__ msum,
        const float* __restrict__ msqrt,
        const float* __restrict__ w1,
        const float* __restrict__ b1,
        const float* __restrict__ w2,
        const float* __restrict__ b2,
        float* __restrict__ out) {
    __shared__ float m_s[HWN];
    __shared__ float p_s[P3C];
    __shared__ float part_s[NW * SEH];
    __shared__ float hid_s[SEH];
    __shared__ float g_s[CC];
    __shared__ float be_s[CC];

    const int tid  = threadIdx.x;
    const int lane = tid & 63;
    const int wv   = tid >> 6;
    const int b    = blockIdx.x;

    const float* xb = x + (size_t)b * SLICE;

    if (tid < HWN) m_s[tid] = mask[(size_t)b * HWN + tid];
    __syncthreads();

    const float inv_div = 1.0f / msum[b];
    const float bscale  = (msqrt[b] - 14.0f) * 0.1f;

    const int  i5   = lane + 320;
    const int  a5   = (i5 < HWN) ? i5 : (HWN - 1);
    const bool tail = (lane < 41);

    unsigned pk[16][3];

    #pragma unroll
    for (int k = 0; k < 16; k += 2) {
        const int c0 = wv * 16 + k;
        const float* r0 = xb + c0 * HWN;
        const float* r1 = r0 + HWN;
        float v[6], w[6];
        #pragma unroll
        for (int ii = 0; ii < 5; ++ii) {
            v[ii] = r0[lane + ii * 64];
            w[ii] = r1[lane + ii * 64];
        }
        v[5] = r0[a5];
        w[5] = r1[a5];

        pk[k][0]     = pack2(v[0], v[1]);
        pk[k][1]     = pack2(v[2], v[3]);
        pk[k][2]     = pack2(v[4], v[5]);
        pk[k + 1][0] = pack2(w[0], w[1]);
        pk[k + 1][1] = pack2(w[2], w[3]);
        pk[k + 1][2] = pack2(w[4], w[5]);
        asm volatile("" : "+v"(pk[k][0]), "+v"(pk[k][1]), "+v"(pk[k][2]),
                          "+v"(pk[k+1][0]), "+v"(pk[k+1][1]), "+v"(pk[k+1][2]));

        float s0 = 0.0f, s1 = 0.0f, x0 = -INFINITY, x1 = -INFINITY;
        #pragma unroll
        for (int ii = 0; ii < 5; ++ii) {
            const float pen = (1.0f - m_s[lane + ii * 64]) * -5000.0f;
            s0 += v[ii];  x0 = fmaxf(x0, v[ii] + pen);
            s1 += w[ii];  x1 = fmaxf(x1, w[ii] + pen);
        }
        if (tail) {
            const float pen = (1.0f - m_s[i5]) * -5000.0f;
            s0 += v[5];   x0 = fmaxf(x0, v[5] + pen);
            s1 += w[5];   x1 = fmaxf(x1, w[5] + pen);
        }
        #pragma unroll
        for (int off = 32; off; off >>= 1) {
            s0 += __shfl_xor(s0, off);  x0 = fmaxf(x0, __shfl_xor(x0, off));
            s1 += __shfl_xor(s1, off);  x1 = fmaxf(x1, __shfl_xor(x1, off));
        }
        if (lane == 0) {
            const float mean0 = s0 * inv_div, mean1 = s1 * inv_div;
            p_s[c0]           = mean0;
            p_s[256 + c0]     = mean0 * bscale;
            p_s[512 + c0]     = x0;
            p_s[c0 + 1]       = mean1;
            p_s[256 + c0 + 1] = mean1 * bscale;
            p_s[512 + c0 + 1] = x1;
        }
    }
    __syncthreads();

    {
        const int q = tid >> 6, s = tid & 63;
        const float* w1r = w1  + s * P3C + q * 48;
        const float* pp  = p_s + q * 48;
        float acc = 0.0f;
        #pragma unroll 8
        for (int j = 0; j < 48; ++j) acc = fmaf(pp[j], w1r[j], acc);
        part_s[q * SEH + s] = acc;
    }
    __syncthreads();
    if (tid < SEH) {
        float h = b1[tid];
        #pragma unroll
        for (int q = 0; q < NW; ++q) h += part_s[q * SEH + tid];
        hid_s[tid] = fmaxf(h, 0.0f);
    }
    __syncthreads();

    if (tid < 512) {
        float a = b2[tid];
        const float* w2r = w2 + (size_t)tid * SEH;
        #pragma unroll 8
        for (int ss = 0; ss < SEH; ++ss) a = fmaf(hid_s[ss], w2r[ss], a);
        if (tid < 256) g_s[tid]        = 1.0f / (1.0f + __expf(-a));
        else           be_s[tid - 256] = a;
    }
    __syncthreads();

    float* ob = out + (size_t)b * SLICE;
    #pragma unroll
    for (int k = 0; k < 16; ++k) {
        const int c  = wv * 16 + k;
        const float g  = g_s[c];
        const float be = be_s[c];
        float* orow = ob + c * HWN;
        const f16x2 h0 = __builtin_bit_cast(f16x2, pk[k][0]);
        const f16x2 h1 = __builtin_bit_cast(f16x2, pk[k][1]);
        const f16x2 h2 = __builtin_bit_cast(f16x2, pk[k][2]);
        orow[lane]       = fmaf(g, (float)h0[0], be) * m_s[lane];
        orow[lane + 64]  = fmaf(g, (float)h0[1], be) * m_s[lane + 64];
        orow[lane + 128] = fmaf(g, (float)h1[0], be) * m_s[lane + 128];
        orow[lane + 192] = fmaf(g, (float)h1[1], be) * m_s[lane + 192];
        orow[lane + 256] = fmaf(g, (float)h2[0], be) * m_s[lane + 256];
        if (tail)
            orow[i5]     = fmaf(g, (float)h2[1], be) * m_s[i5];
    }
}

extern "C" void kernel_launch(void* const* d_in, const int* in_sizes, int n_in,
                              void* d_out, int out_size, void* d_ws, size_t ws_size,
                              hipStream_t stream) {
    const float* x     = (const float*)d_in[0];
    const float* mask  = (const float*)d_in[1];
    const float* msum  = (const float*)d_in[2];
    const float* msqrt = (const float*)d_in[3];
    const float* w1    = (const float*)d_in[4];
    const float* b1    = (const float*)d_in[5];
    const float* w2    = (const float*)d_in[6];
    const float* b2    = (const float*)d_in[7];
    float* out = (float*)d_out;

    const size_t n_copy_dw = (size_t)BB * CC * 192;              // 50.3M dwords
    const size_t need = n_copy_dw * 4 + (size_t)BB * P3C * 4
                      + (size_t)BB * 512 * 4;                    // ~206.6 MB

    if (ws_size >= need) {
        unsigned* wsd    = (unsigned*)d_ws;
        float*    pooled = (float*)((char*)d_ws + n_copy_dw * 4);
        float*    gb     = pooled + (size_t)BB * P3C;

        k_pool_copy<<<BB,     1024, 0, stream>>>(x, mask, msum, msqrt, wsd, pooled);
        k_mlp      <<<BB / 4,  256, 0, stream>>>(pooled, w1, b1, w2, b2, gb);
        k_apply_f16<<<BB,     1024, 0, stream>>>(wsd, mask, gb, out);
    } else {
        k_se_fused<<<BB, 1024, 0, stream>>>(x, mask, msum, msqrt,
                                            w1, b1, w2, b2, out);
    }
}